// Round 2
// baseline (395.325 us; speedup 1.0000x reference)
//
#include <hip/hip_runtime.h>
#include <math.h>

// Problem constants (B=64, N=197, D=768, H=3072, R=16, K=1)
// All inputs/outputs are FP32 (per reference). Internally: bf16 MFMA GEMMs.
#define M_ROWS 12608   // 64*197
#define D_DIM  768
#define H_DIM  3072

typedef __bf16 bf16_t;
typedef __bf16 bf16x8 __attribute__((ext_vector_type(8)));
typedef float  f32x4  __attribute__((ext_vector_type(4)));

// Async global->LDS, 16B per lane. LDS dest is wave-uniform base + lane*16.
__device__ __forceinline__ void gl2lds16(const bf16_t* g, bf16_t* l) {
  __builtin_amdgcn_global_load_lds(
      (__attribute__((address_space(1))) void*)g,
      (__attribute__((address_space(3))) void*)l,
      16, 0, 0);
}

// fp32 -> bf16 elementwise cast (4 elems/thread)
__global__ void cast_f32_bf16_kernel(const float* __restrict__ in,
                                     bf16_t* __restrict__ out, long n) {
  long i = ((long)blockIdx.x * 256 + threadIdx.x) * 4;
  if (i + 3 < n) {
    float4 v = *(const float4*)(in + i);
    out[i + 0] = (bf16_t)v.x; out[i + 1] = (bf16_t)v.y;
    out[i + 2] = (bf16_t)v.z; out[i + 3] = (bf16_t)v.w;
  } else {
    for (; i < n; ++i) out[i] = (bf16_t)in[i];
  }
}

// Weff[o][i] = W[o][i] + sum_r Bm[o][r] * A[r][i]  (fp32 in, bf16 out)
__global__ void fold_lora_kernel(const float* __restrict__ W,
                                 const float* __restrict__ A,
                                 const float* __restrict__ Bm,
                                 bf16_t* __restrict__ Weff,
                                 int OUT, int IN) {
  long idx = (long)blockIdx.x * 256 + threadIdx.x;
  if (idx >= (long)OUT * IN) return;
  int o = (int)(idx / IN);
  int i = (int)(idx - (long)o * IN);
  float s = W[idx];
#pragma unroll
  for (int r = 0; r < 16; ++r)
    s += Bm[o * 16 + r] * A[r * IN + i];
  Weff[idx] = (bf16_t)s;
}

// C[m][n] = act( sum_k A[m][k]*B[n][k] + bias[n] ), A:[M,Kd] B:[N,Kd] bf16.
// 128x128 tile, 4 waves 2x2, each wave 64x64 via 4x4 16x16x32 bf16 MFMAs.
// Output type templated: bf16 for the intermediate h, float for final out.
template <bool GELU, typename OutT>
__global__ __launch_bounds__(256) void gemm_bt_kernel(
    const bf16_t* __restrict__ Amat, const bf16_t* __restrict__ Bmat,
    const float* __restrict__ bias, OutT* __restrict__ Cmat,
    int Mrows, int Ncols, int Kd) {
  __shared__ bf16_t sA[128 * 32];
  __shared__ bf16_t sB[128 * 32];
  const int tid  = threadIdx.x;
  const int lane = tid & 63;
  const int wave = tid >> 6;
  const int wm = wave & 1, wn = wave >> 1;
  const int row0 = blockIdx.y * 128;
  const int col0 = blockIdx.x * 128;

  // staging: tile is [128 rows][32 k] bf16 = 512 chunks of 16B (8 bf16).
  // chunk j -> row j>>2, kcol (j&3)*8. Thread stages chunks tid and tid+256.
  const int j0 = tid, j1 = tid + 256;
  int ra0 = row0 + (j0 >> 2); if (ra0 > Mrows - 1) ra0 = Mrows - 1;  // M-edge clamp
  int ra1 = row0 + (j1 >> 2); if (ra1 > Mrows - 1) ra1 = Mrows - 1;
  const bf16_t* gA0 = Amat + (size_t)ra0 * Kd + (j0 & 3) * 8;
  const bf16_t* gA1 = Amat + (size_t)ra1 * Kd + (j1 & 3) * 8;
  const bf16_t* gB0 = Bmat + (size_t)(col0 + (j0 >> 2)) * Kd + (j0 & 3) * 8;
  const bf16_t* gB1 = Bmat + (size_t)(col0 + (j1 >> 2)) * Kd + (j1 & 3) * 8;

  // wave-uniform LDS bases: lane's 16B lands at base + lane*16 -> chunk id matches j0/j1
  bf16_t* sA0 = sA + (wave * 64) * 8;
  bf16_t* sA1 = sA + (256 + wave * 64) * 8;
  bf16_t* sB0 = sB + (wave * 64) * 8;
  bf16_t* sB1 = sB + (256 + wave * 64) * 8;

  // MFMA fragment element-offsets in the [128][32] LDS tiles.
  const int koff = (lane >> 4) * 8;
  int aoffs[4], boffs[4];
#pragma unroll
  for (int i = 0; i < 4; ++i) {
    aoffs[i] = (wm * 64 + i * 16 + (lane & 15)) * 32 + koff;
    boffs[i] = (wn * 64 + i * 16 + (lane & 15)) * 32 + koff;
  }

  f32x4 acc[4][4] = {};

  const int iters = Kd / 32;  // Kd in {768, 3072}: exact
  for (int it = 0; it < iters; ++it) {
    gl2lds16(gA0, sA0);
    gl2lds16(gA1, sA1);
    gl2lds16(gB0, sB0);
    gl2lds16(gB1, sB1);
    gA0 += 32; gA1 += 32; gB0 += 32; gB1 += 32;
    __syncthreads();  // compiler drains vmcnt before s_barrier

    bf16x8 af[4], bfr[4];
#pragma unroll
    for (int i = 0; i < 4; ++i) af[i]  = *(const bf16x8*)(sA + aoffs[i]);
#pragma unroll
    for (int i = 0; i < 4; ++i) bfr[i] = *(const bf16x8*)(sB + boffs[i]);
#pragma unroll
    for (int mi = 0; mi < 4; ++mi)
#pragma unroll
      for (int ni = 0; ni < 4; ++ni)
        acc[mi][ni] = __builtin_amdgcn_mfma_f32_16x16x32_bf16(
            af[mi], bfr[ni], acc[mi][ni], 0, 0, 0);
    __syncthreads();  // all reads done before next stage overwrites
  }

  // epilogue: C/D lane layout col=lane&15, row=(lane>>4)*4+reg  [m89-verified]
  const int crow = (lane >> 4) * 4;
  const int ccol = lane & 15;
#pragma unroll
  for (int ni = 0; ni < 4; ++ni) {
    const int gc = col0 + wn * 64 + ni * 16 + ccol;
    const float bv = bias[gc];
#pragma unroll
    for (int mi = 0; mi < 4; ++mi) {
      const int gr = row0 + wm * 64 + mi * 16 + crow;
#pragma unroll
      for (int r = 0; r < 4; ++r) {
        const int row = gr + r;
        if (row < Mrows) {
          float v = acc[mi][ni][r] + bv;
          if (GELU) v = 0.5f * v * (1.0f + erff(v * 0.70710678118654752f));
          Cmat[(size_t)row * Ncols + gc] = (OutT)v;
        }
      }
    }
  }
}

extern "C" void kernel_launch(void* const* d_in, const int* in_sizes, int n_in,
                              void* d_out, int out_size, void* d_ws, size_t ws_size,
                              hipStream_t stream) {
  const float* x  = (const float*)d_in[0];
  const float* W1 = (const float*)d_in[1];
  const float* b1 = (const float*)d_in[2];
  const float* A1 = (const float*)d_in[3];
  const float* B1 = (const float*)d_in[4];
  const float* W2 = (const float*)d_in[5];
  const float* b2 = (const float*)d_in[6];
  const float* A2 = (const float*)d_in[7];
  const float* B2 = (const float*)d_in[8];
  float* out = (float*)d_out;

  // workspace layout (256B-aligned):
  //   xb   : 12608*768*2  = 19,365,888 B  (pad to 19,366,144)
  //   W1eff: 3072*768*2   =  4,718,592 B
  //   W2eff: 768*3072*2   =  4,718,592 B
  //   hbuf : 12608*3072*2 = 77,463,552 B   (total ~106.3 MB)
  char* ws = (char*)d_ws;
  bf16_t* xb    = (bf16_t*)ws;
  bf16_t* W1eff = (bf16_t*)(ws + 19366144);
  bf16_t* W2eff = (bf16_t*)(ws + 19366144 + 4718592);
  bf16_t* hbuf  = (bf16_t*)(ws + 19366144 + 2 * 4718592);

  const long nx = (long)M_ROWS * D_DIM;
  cast_f32_bf16_kernel<<<(int)((nx / 4 + 255) / 256), 256, 0, stream>>>(x, xb, nx);

  const int foldBlocks = (H_DIM * D_DIM + 255) / 256;
  fold_lora_kernel<<<foldBlocks, 256, 0, stream>>>(W1, A1, B1, W1eff, H_DIM, D_DIM);
  fold_lora_kernel<<<foldBlocks, 256, 0, stream>>>(W2, A2, B2, W2eff, D_DIM, H_DIM);

  // GEMM1 + bias + exact GELU -> hbuf (bf16) [M, H]
  gemm_bt_kernel<true, bf16_t><<<dim3(H_DIM / 128, (M_ROWS + 127) / 128), 256, 0, stream>>>(
      xb, W1eff, b1, hbuf, M_ROWS, H_DIM, D_DIM);
  // GEMM2 + bias -> out (fp32) [M, D]
  gemm_bt_kernel<false, float><<<dim3(D_DIM / 128, (M_ROWS + 127) / 128), 256, 0, stream>>>(
      hbuf, W2eff, b2, out, M_ROWS, D_DIM, H_DIM);
}

// Round 4
// 341.855 us; speedup vs baseline: 1.1564x; 1.1564x over previous
//
#include <hip/hip_runtime.h>
#include <math.h>

// LoRA-MLP, fp32 in/out. Fold rank-16 LoRA into weights (K=1), then two
// bf16 MFMA GEMMs: h = gelu(x@W1eff^T + b1); out = h@W2eff^T + b2.
#define M_ROWS 12608   // 64*197
#define D_DIM  768
#define H_DIM  3072

typedef __bf16 bf16_t;
typedef __bf16 bf16x8 __attribute__((ext_vector_type(8)));
typedef float  f32x4  __attribute__((ext_vector_type(4)));

__device__ __forceinline__ void gl2lds16(const bf16_t* g, bf16_t* l) {
  __builtin_amdgcn_global_load_lds(
      (__attribute__((address_space(1))) void*)g,
      (__attribute__((address_space(3))) void*)l,
      16, 0, 0);
}

// Exact GELU: 0.5*v*(1+erf(v/sqrt2)); erf via Abramowitz-Stegun 7.1.26
// (|erf err|<=1.5e-7). NOTE: erf argument IS scaled by 1/sqrt2 (round-3 bug).
__device__ __forceinline__ float gelu_fast(float v) {
  float xs = v * 0.70710678118654752f;
  float ax = fabsf(xs);
  float t = __builtin_amdgcn_rcpf(1.0f + 0.3275911f * ax);
  float poly = t * (0.254829592f +
              t * (-0.284496736f +
              t * (1.421413741f +
              t * (-1.453152027f +
              t * 1.061405429f))));
  float er = 1.0f - poly * __expf(-ax * ax);
  er = (xs < 0.0f) ? -er : er;
  return 0.5f * v * (1.0f + er);
}

__global__ void cast_f32_bf16_kernel(const float* __restrict__ in,
                                     bf16_t* __restrict__ out, long n) {
  long i = ((long)blockIdx.x * 256 + threadIdx.x) * 4;
  if (i + 3 < n) {
    float4 v = *(const float4*)(in + i);
    out[i + 0] = (bf16_t)v.x; out[i + 1] = (bf16_t)v.y;
    out[i + 2] = (bf16_t)v.z; out[i + 3] = (bf16_t)v.w;
  } else {
    for (; i < n; ++i) out[i] = (bf16_t)in[i];
  }
}

// Weff[o][i] = W[o][i] + sum_r Bm[o][r]*A[r][i]  (fp32 in, bf16 out)
__global__ void fold_lora_kernel(const float* __restrict__ W,
                                 const float* __restrict__ A,
                                 const float* __restrict__ Bm,
                                 bf16_t* __restrict__ Weff,
                                 int OUT, int IN) {
  long idx = (long)blockIdx.x * 256 + threadIdx.x;
  if (idx >= (long)OUT * IN) return;
  int o = (int)(idx / IN);
  int i = (int)(idx - (long)o * IN);
  float s = W[idx];
#pragma unroll
  for (int r = 0; r < 16; ++r)
    s += Bm[o * 16 + r] * A[r * IN + i];
  Weff[idx] = (bf16_t)s;
}

// ---------------- GEMM1: 256x128 block, 128x64 wave (8x4 acc), fused GELU,
// XOR-swizzled LDS ([rows][32] bf16; chunk (row,kc) stored at kc^((row>>1)&3)),
// coalesced bf16 stores via LDS-transpose epilogue. -----------------
__global__ __launch_bounds__(256, 2) void gemm1_kernel(
    const bf16_t* __restrict__ Amat, const bf16_t* __restrict__ Bmat,
    const float* __restrict__ bias, bf16_t* __restrict__ Cmat,
    int Mrows, int Ncols, int Kd) {
  __shared__ char smem[24576];                 // 16KB sA + 8KB sB; reused as 16.9KB sT
  bf16_t* sA = (bf16_t*)smem;                  // [256][32]
  bf16_t* sB = (bf16_t*)(smem + 16384);        // [128][32]
  float*  sT = (float*)smem;                   // [32][132] epilogue

  const int tid = threadIdx.x, lane = tid & 63, wave = tid >> 6;
  const int wm = wave & 1, wn = wave >> 1;
  const int row0 = blockIdx.y * 256, col0 = blockIdx.x * 128;

  // staging: A = 1024 16B-chunks (4/thread), B = 512 (2/thread).
  // LDS chunk c holds global (row=c>>2, kc=(c&3)^((row>>1)&3)).
  const bf16_t* gA[4]; const bf16_t* gB[2];
  bf16_t* lA[4]; bf16_t* lB[2];
#pragma unroll
  for (int q = 0; q < 4; ++q) {
    int c = tid + q * 256;
    int r = c >> 2;
    int kcg = (c & 3) ^ ((r >> 1) & 3);
    int ra = row0 + r; if (ra > Mrows - 1) ra = Mrows - 1;
    gA[q] = Amat + (size_t)ra * Kd + kcg * 8;
    lA[q] = sA + (q * 256 + wave * 64) * 8;
  }
#pragma unroll
  for (int q = 0; q < 2; ++q) {
    int c = tid + q * 256;
    int r = c >> 2;
    int kcg = (c & 3) ^ ((r >> 1) & 3);
    gB[q] = Bmat + (size_t)(col0 + r) * Kd + kcg * 8;
    lB[q] = sB + (q * 256 + wave * 64) * 8;
  }

  // fragment read offsets (swizzle-aware)
  const int rl = lane & 15, kc = lane >> 4;
  int aoffs[8], boffs[4];
#pragma unroll
  for (int i = 0; i < 8; ++i) {
    int r = wm * 128 + i * 16 + rl;
    aoffs[i] = r * 32 + ((kc ^ ((r >> 1) & 3)) * 8);
  }
#pragma unroll
  for (int j = 0; j < 4; ++j) {
    int r = wn * 64 + j * 16 + rl;
    boffs[j] = r * 32 + ((kc ^ ((r >> 1) & 3)) * 8);
  }

  f32x4 acc[8][4] = {};
  const int iters = Kd / 32;
  for (int it = 0; it < iters; ++it) {
#pragma unroll
    for (int q = 0; q < 4; ++q) gl2lds16(gA[q], lA[q]);
#pragma unroll
    for (int q = 0; q < 2; ++q) gl2lds16(gB[q], lB[q]);
#pragma unroll
    for (int q = 0; q < 4; ++q) gA[q] += 32;
#pragma unroll
    for (int q = 0; q < 2; ++q) gB[q] += 32;
    __syncthreads();

    bf16x8 af[8], bfr[4];
#pragma unroll
    for (int i = 0; i < 8; ++i) af[i] = *(const bf16x8*)(sA + aoffs[i]);
#pragma unroll
    for (int j = 0; j < 4; ++j) bfr[j] = *(const bf16x8*)(sB + boffs[j]);
#pragma unroll
    for (int i = 0; i < 8; ++i)
#pragma unroll
      for (int j = 0; j < 4; ++j)
        acc[i][j] = __builtin_amdgcn_mfma_f32_16x16x32_bf16(
            af[i], bfr[j], acc[i][j], 0, 0, 0);
    __syncthreads();
  }

  // epilogue: 8 passes; pass mi stages 32 rows x 128 cols f32 in sT (stride 132),
  // then 256 threads each gelu+store 16 contiguous bf16 (fully coalesced).
  const int crow = (lane >> 4) * 4, ccol = lane & 15;
  const int erow = tid >> 3, eseg = tid & 7;
#pragma unroll
  for (int mi = 0; mi < 8; ++mi) {
#pragma unroll
    for (int ni = 0; ni < 4; ++ni)
#pragma unroll
      for (int r = 0; r < 4; ++r)
        sT[(wm * 16 + crow + r) * 132 + wn * 64 + ni * 16 + ccol] = acc[mi][ni][r];
    __syncthreads();
    const int grow = row0 + (erow >> 4) * 128 + mi * 16 + (erow & 15);
    if (grow < Mrows) {
      const float* src = sT + erow * 132 + eseg * 16;
      bf16_t ov[16];
#pragma unroll
      for (int p = 0; p < 16; ++p) {
        float v = src[p] + bias[col0 + eseg * 16 + p];
        ov[p] = (bf16_t)gelu_fast(v);
      }
      bf16_t* dst = Cmat + (size_t)grow * Ncols + col0 + eseg * 16;
      *(bf16x8*)dst = *(bf16x8*)ov;
      *(bf16x8*)(dst + 8) = *(bf16x8*)(ov + 8);
    }
    __syncthreads();
  }
}

// ---------------- GEMM2: 128x128 block, 64x64 wave (4x4 acc), swizzled LDS,
// fp32 out + bias (f32 scalar stores already make full 64B lines). ---------
__global__ __launch_bounds__(256) void gemm2_kernel(
    const bf16_t* __restrict__ Amat, const bf16_t* __restrict__ Bmat,
    const float* __restrict__ bias, float* __restrict__ Cmat,
    int Mrows, int Ncols, int Kd) {
  __shared__ bf16_t sA[128 * 32];
  __shared__ bf16_t sB[128 * 32];
  const int tid = threadIdx.x, lane = tid & 63, wave = tid >> 6;
  const int wm = wave & 1, wn = wave >> 1;
  const int row0 = blockIdx.y * 128, col0 = blockIdx.x * 128;

  const bf16_t* gA[2]; const bf16_t* gB[2];
  bf16_t* lA[2]; bf16_t* lB[2];
#pragma unroll
  for (int q = 0; q < 2; ++q) {
    int c = tid + q * 256;
    int r = c >> 2;
    int kcg = (c & 3) ^ ((r >> 1) & 3);
    int ra = row0 + r; if (ra > Mrows - 1) ra = Mrows - 1;
    gA[q] = Amat + (size_t)ra * Kd + kcg * 8;
    lA[q] = sA + (q * 256 + wave * 64) * 8;
    gB[q] = Bmat + (size_t)(col0 + r) * Kd + kcg * 8;
    lB[q] = sB + (q * 256 + wave * 64) * 8;
  }

  const int rl = lane & 15, kc = lane >> 4;
  int aoffs[4], boffs[4];
#pragma unroll
  for (int i = 0; i < 4; ++i) {
    int ra = wm * 64 + i * 16 + rl;
    int rb = wn * 64 + i * 16 + rl;
    aoffs[i] = ra * 32 + ((kc ^ ((ra >> 1) & 3)) * 8);
    boffs[i] = rb * 32 + ((kc ^ ((rb >> 1) & 3)) * 8);
  }

  f32x4 acc[4][4] = {};
  const int iters = Kd / 32;
  for (int it = 0; it < iters; ++it) {
#pragma unroll
    for (int q = 0; q < 2; ++q) gl2lds16(gA[q], lA[q]);
#pragma unroll
    for (int q = 0; q < 2; ++q) gl2lds16(gB[q], lB[q]);
#pragma unroll
    for (int q = 0; q < 2; ++q) { gA[q] += 32; gB[q] += 32; }
    __syncthreads();

    bf16x8 af[4], bfr[4];
#pragma unroll
    for (int i = 0; i < 4; ++i) af[i] = *(const bf16x8*)(sA + aoffs[i]);
#pragma unroll
    for (int i = 0; i < 4; ++i) bfr[i] = *(const bf16x8*)(sB + boffs[i]);
#pragma unroll
    for (int mi = 0; mi < 4; ++mi)
#pragma unroll
      for (int ni = 0; ni < 4; ++ni)
        acc[mi][ni] = __builtin_amdgcn_mfma_f32_16x16x32_bf16(
            af[mi], bfr[ni], acc[mi][ni], 0, 0, 0);
    __syncthreads();
  }

  const int crow = (lane >> 4) * 4, ccol = lane & 15;
#pragma unroll
  for (int ni = 0; ni < 4; ++ni) {
    const int gc = col0 + wn * 64 + ni * 16 + ccol;
    const float bv = bias[gc];
#pragma unroll
    for (int mi = 0; mi < 4; ++mi) {
      const int gr = row0 + wm * 64 + mi * 16 + crow;
#pragma unroll
      for (int r = 0; r < 4; ++r) {
        const int row = gr + r;
        if (row < Mrows)
          Cmat[(size_t)row * Ncols + gc] = acc[mi][ni][r] + bv;
      }
    }
  }
}

extern "C" void kernel_launch(void* const* d_in, const int* in_sizes, int n_in,
                              void* d_out, int out_size, void* d_ws, size_t ws_size,
                              hipStream_t stream) {
  const float* x  = (const float*)d_in[0];
  const float* W1 = (const float*)d_in[1];
  const float* b1 = (const float*)d_in[2];
  const float* A1 = (const float*)d_in[3];
  const float* B1 = (const float*)d_in[4];
  const float* W2 = (const float*)d_in[5];
  const float* b2 = (const float*)d_in[6];
  const float* A2 = (const float*)d_in[7];
  const float* B2 = (const float*)d_in[8];
  float* out = (float*)d_out;

  char* ws = (char*)d_ws;
  bf16_t* xb    = (bf16_t*)ws;                             // 19,365,888 B (pad)
  bf16_t* W1eff = (bf16_t*)(ws + 19366144);                //  4,718,592 B
  bf16_t* W2eff = (bf16_t*)(ws + 19366144 + 4718592);      //  4,718,592 B
  bf16_t* hbuf  = (bf16_t*)(ws + 19366144 + 2 * 4718592);  // 77,463,552 B

  const long nx = (long)M_ROWS * D_DIM;
  cast_f32_bf16_kernel<<<(int)((nx / 4 + 255) / 256), 256, 0, stream>>>(x, xb, nx);

  const int foldBlocks = (H_DIM * D_DIM + 255) / 256;
  fold_lora_kernel<<<foldBlocks, 256, 0, stream>>>(W1, A1, B1, W1eff, H_DIM, D_DIM);
  fold_lora_kernel<<<foldBlocks, 256, 0, stream>>>(W2, A2, B2, W2eff, D_DIM, H_DIM);

  // GEMM1: 256x128 tiles -> grid (24, 50)
  gemm1_kernel<<<dim3(H_DIM / 128, (M_ROWS + 255) / 256), 256, 0, stream>>>(
      xb, W1eff, b1, hbuf, M_ROWS, H_DIM, D_DIM);
  // GEMM2: 128x128 tiles -> grid (6, 99)
  gemm2_kernel<<<dim3(D_DIM / 128, (M_ROWS + 127) / 128), 256, 0, stream>>>(
      hbuf, W2eff, b2, out, M_ROWS, D_DIM, H_DIM);
}

// Round 5
// 302.346 us; speedup vs baseline: 1.3075x; 1.1307x over previous
//
#include <hip/hip_runtime.h>
#include <math.h>

// LoRA-MLP, fp32 in/out. Fold rank-16 LoRA into weights (K=1), then two
// bf16 MFMA GEMMs: h = gelu(x@W1eff^T + b1); out = h@W2eff^T + b2.
#define M_ROWS 12608   // 64*197
#define D_DIM  768
#define H_DIM  3072

typedef __bf16 bf16_t;
typedef __bf16 bf16x8 __attribute__((ext_vector_type(8)));
typedef float  f32x4  __attribute__((ext_vector_type(4)));

__device__ __forceinline__ void gl2lds16(const bf16_t* g, bf16_t* l) {
  __builtin_amdgcn_global_load_lds(
      (__attribute__((address_space(1))) void*)g,
      (__attribute__((address_space(3))) void*)l,
      16, 0, 0);
}

// Exact GELU: 0.5*v*(1+erf(v/sqrt2)); erf via Abramowitz-Stegun 7.1.26.
__device__ __forceinline__ float gelu_fast(float v) {
  float xs = v * 0.70710678118654752f;
  float ax = fabsf(xs);
  float t = __builtin_amdgcn_rcpf(1.0f + 0.3275911f * ax);
  float poly = t * (0.254829592f +
              t * (-0.284496736f +
              t * (1.421413741f +
              t * (-1.453152027f +
              t * 1.061405429f))));
  float er = 1.0f - poly * __expf(-ax * ax);
  er = (xs < 0.0f) ? -er : er;
  return 0.5f * v * (1.0f + er);
}

__global__ void cast_f32_bf16_kernel(const float* __restrict__ in,
                                     bf16_t* __restrict__ out, long n) {
  long i = ((long)blockIdx.x * 256 + threadIdx.x) * 4;
  if (i + 3 < n) {
    float4 v = *(const float4*)(in + i);
    out[i + 0] = (bf16_t)v.x; out[i + 1] = (bf16_t)v.y;
    out[i + 2] = (bf16_t)v.z; out[i + 3] = (bf16_t)v.w;
  } else {
    for (; i < n; ++i) out[i] = (bf16_t)in[i];
  }
}

// Weff[o][i] = W[o][i] + sum_r Bm[o][r]*A[r][i]  (fp32 in, bf16 out)
__global__ void fold_lora_kernel(const float* __restrict__ W,
                                 const float* __restrict__ A,
                                 const float* __restrict__ Bm,
                                 bf16_t* __restrict__ Weff,
                                 int OUT, int IN) {
  long idx = (long)blockIdx.x * 256 + threadIdx.x;
  if (idx >= (long)OUT * IN) return;
  int o = (int)(idx / IN);
  int i = (int)(idx - (long)o * IN);
  float s = W[idx];
#pragma unroll
  for (int r = 0; r < 16; ++r)
    s += Bm[o * 16 + r] * A[r * IN + i];
  Weff[idx] = (bf16_t)s;
}

// ---------------- GEMM1: 256x128 block, BK=64, 128x64 wave (8x4 acc), fused
// GELU, XOR-swizzled LDS (chunk (row,kk) at slot kk^(row&7), 8 spans of 16B),
// XCD-banded 1-D grid, coalesced bf16 stores via LDS-transpose epilogue.
__global__ __launch_bounds__(256, 2) void gemm1_kernel(
    const bf16_t* __restrict__ Amat, const bf16_t* __restrict__ Bmat,
    const float* __restrict__ bias, bf16_t* __restrict__ Cmat,
    int Mrows, int Ncols, int Kd) {
  __shared__ char smem[49152];                 // 32KB sA + 16KB sB; sT reuses
  bf16_t* sA = (bf16_t*)smem;                  // [256][64]
  bf16_t* sB = (bf16_t*)(smem + 32768);        // [128][64]
  float*  sT = (float*)smem;                   // [32][132] epilogue

  // XCD-banded swizzle: rows 0..49 (pad 56), cols 0..23. Same-row col-tiles
  // land on one XCD consecutively -> A-slice fetched once per L2.
  {
  }
  const int gswz = blockIdx.x;
  const int xcd = gswz & 7, tswz = gswz >> 3;
  const int colb = tswz % 24, rband = tswz / 24;
  const int rowb = rband * 8 + xcd;
  if (rowb >= 50) return;
  const int row0 = rowb * 256, col0 = colb * 128;

  const int tid = threadIdx.x, lane = tid & 63, wave = tid >> 6;
  const int wm = wave & 1, wn = wave >> 1;

  // staging: A = 2048 16B-chunks (8/thread), B = 1024 (4/thread).
  // chunk c -> row c>>3, LDS slot kk=c&7 holds global k-chunk kk^(row&7).
  const bf16_t* gA[8]; const bf16_t* gB[4];
  bf16_t* lA[8]; bf16_t* lB[4];
#pragma unroll
  for (int q = 0; q < 8; ++q) {
    int c = tid + q * 256;
    int r = c >> 3;
    int kkg = (c & 7) ^ (r & 7);
    int ra = row0 + r; if (ra > Mrows - 1) ra = Mrows - 1;
    gA[q] = Amat + (size_t)ra * Kd + kkg * 8;
    lA[q] = sA + (q * 256 + wave * 64) * 8;
  }
#pragma unroll
  for (int q = 0; q < 4; ++q) {
    int c = tid + q * 256;
    int r = c >> 3;
    int kkg = (c & 7) ^ (r & 7);
    gB[q] = Bmat + (size_t)(col0 + r) * Kd + kkg * 8;
    lB[q] = sB + (q * 256 + wave * 64) * 8;
  }

  // fragment offsets for ks=0 (ks=1 -> ^32): granule = (kc^(r&3)) + ((r>>2)&1)*4
  const int rl = lane & 15, kc = lane >> 4;
  int aoffs[8], boffs[4];
#pragma unroll
  for (int i = 0; i < 8; ++i) {
    int r = wm * 128 + i * 16 + rl;
    aoffs[i] = r * 64 + ((kc ^ (r & 3)) + ((r >> 2) & 1) * 4) * 8;
  }
#pragma unroll
  for (int j = 0; j < 4; ++j) {
    int r = wn * 64 + j * 16 + rl;
    boffs[j] = r * 64 + ((kc ^ (r & 3)) + ((r >> 2) & 1) * 4) * 8;
  }

  f32x4 acc[8][4] = {};
  const int iters = Kd / 64;
  for (int it = 0; it < iters; ++it) {
#pragma unroll
    for (int q = 0; q < 8; ++q) gl2lds16(gA[q], lA[q]);
#pragma unroll
    for (int q = 0; q < 4; ++q) gl2lds16(gB[q], lB[q]);
#pragma unroll
    for (int q = 0; q < 8; ++q) gA[q] += 64;
#pragma unroll
    for (int q = 0; q < 4; ++q) gB[q] += 64;
    __syncthreads();

#pragma unroll
    for (int ks = 0; ks < 2; ++ks) {
      bf16x8 af[8], bfr[4];
#pragma unroll
      for (int i = 0; i < 8; ++i) af[i] = *(const bf16x8*)(sA + (aoffs[i] ^ (ks * 32)));
#pragma unroll
      for (int j = 0; j < 4; ++j) bfr[j] = *(const bf16x8*)(sB + (boffs[j] ^ (ks * 32)));
#pragma unroll
      for (int i = 0; i < 8; ++i)
#pragma unroll
        for (int j = 0; j < 4; ++j)
          acc[i][j] = __builtin_amdgcn_mfma_f32_16x16x32_bf16(
              af[i], bfr[j], acc[i][j], 0, 0, 0);
    }
    __syncthreads();
  }

  // epilogue: 8 passes; pass mi stages 32 rows x 128 cols f32 in sT (stride 132),
  // then 256 threads each gelu+store 16 contiguous bf16 (fully coalesced).
  const int crow = (lane >> 4) * 4, ccol = lane & 15;
  const int erow = tid >> 3, eseg = tid & 7;
#pragma unroll
  for (int mi = 0; mi < 8; ++mi) {
#pragma unroll
    for (int ni = 0; ni < 4; ++ni)
#pragma unroll
      for (int r = 0; r < 4; ++r)
        sT[(wm * 16 + crow + r) * 132 + wn * 64 + ni * 16 + ccol] = acc[mi][ni][r];
    __syncthreads();
    const int grow = row0 + (erow >> 4) * 128 + mi * 16 + (erow & 15);
    if (grow < Mrows) {
      const float* src = sT + erow * 132 + eseg * 16;
      bf16_t ov[16];
#pragma unroll
      for (int p = 0; p < 16; ++p) {
        float v = src[p] + bias[col0 + eseg * 16 + p];
        ov[p] = (bf16_t)gelu_fast(v);
      }
      bf16_t* dst = Cmat + (size_t)grow * Ncols + col0 + eseg * 16;
      *(bf16x8*)dst = *(bf16x8*)ov;
      *(bf16x8*)(dst + 8) = *(bf16x8*)(ov + 8);
    }
    __syncthreads();
  }
}

// ---------------- GEMM2: 128x128 block, BK=64, 64x64 wave (4x4 acc),
// XOR-swizzled LDS, XCD-banded grid, fp32 out + bias. ---------
__global__ __launch_bounds__(256) void gemm2_kernel(
    const bf16_t* __restrict__ Amat, const bf16_t* __restrict__ Bmat,
    const float* __restrict__ bias, float* __restrict__ Cmat,
    int Mrows, int Ncols, int Kd) {
  __shared__ bf16_t sA[128 * 64];
  __shared__ bf16_t sB[128 * 64];

  // XCD-banded swizzle: rows 0..98 (pad 104), cols 0..5.
  const int gswz = blockIdx.x;
  const int xcd = gswz & 7, tswz = gswz >> 3;
  const int colb = tswz % 6, rband = tswz / 6;
  const int rowb = rband * 8 + xcd;
  if (rowb >= 99) return;
  const int row0 = rowb * 128, col0 = colb * 128;

  const int tid = threadIdx.x, lane = tid & 63, wave = tid >> 6;
  const int wm = wave & 1, wn = wave >> 1;

  const bf16_t* gA[4]; const bf16_t* gB[4];
  bf16_t* lA[4]; bf16_t* lB[4];
#pragma unroll
  for (int q = 0; q < 4; ++q) {
    int c = tid + q * 256;
    int r = c >> 3;
    int kkg = (c & 7) ^ (r & 7);
    int ra = row0 + r; if (ra > Mrows - 1) ra = Mrows - 1;
    gA[q] = Amat + (size_t)ra * Kd + kkg * 8;
    lA[q] = sA + (q * 256 + wave * 64) * 8;
    gB[q] = Bmat + (size_t)(col0 + r) * Kd + kkg * 8;
    lB[q] = sB + (q * 256 + wave * 64) * 8;
  }

  const int rl = lane & 15, kc = lane >> 4;
  int aoffs[4], boffs[4];
#pragma unroll
  for (int i = 0; i < 4; ++i) {
    int ra = wm * 64 + i * 16 + rl;
    int rb = wn * 64 + i * 16 + rl;
    aoffs[i] = ra * 64 + ((kc ^ (ra & 3)) + ((ra >> 2) & 1) * 4) * 8;
    boffs[i] = rb * 64 + ((kc ^ (rb & 3)) + ((rb >> 2) & 1) * 4) * 8;
  }

  f32x4 acc[4][4] = {};
  const int iters = Kd / 64;
  for (int it = 0; it < iters; ++it) {
#pragma unroll
    for (int q = 0; q < 4; ++q) gl2lds16(gA[q], lA[q]);
#pragma unroll
    for (int q = 0; q < 4; ++q) gl2lds16(gB[q], lB[q]);
#pragma unroll
    for (int q = 0; q < 4; ++q) { gA[q] += 64; gB[q] += 64; }
    __syncthreads();

#pragma unroll
    for (int ks = 0; ks < 2; ++ks) {
      bf16x8 af[4], bfr[4];
#pragma unroll
      for (int i = 0; i < 4; ++i) af[i] = *(const bf16x8*)(sA + (aoffs[i] ^ (ks * 32)));
#pragma unroll
      for (int i = 0; i < 4; ++i) bfr[i] = *(const bf16x8*)(sB + (boffs[i] ^ (ks * 32)));
#pragma unroll
      for (int mi = 0; mi < 4; ++mi)
#pragma unroll
        for (int ni = 0; ni < 4; ++ni)
          acc[mi][ni] = __builtin_amdgcn_mfma_f32_16x16x32_bf16(
              af[mi], bfr[ni], acc[mi][ni], 0, 0, 0);
    }
    __syncthreads();
  }

  const int crow = (lane >> 4) * 4, ccol = lane & 15;
#pragma unroll
  for (int ni = 0; ni < 4; ++ni) {
    const int gc = col0 + wn * 64 + ni * 16 + ccol;
    const float bv = bias[gc];
#pragma unroll
    for (int mi = 0; mi < 4; ++mi) {
      const int gr = row0 + wm * 64 + mi * 16 + crow;
#pragma unroll
      for (int r = 0; r < 4; ++r) {
        const int row = gr + r;
        if (row < Mrows)
          Cmat[(size_t)row * Ncols + gc] = acc[mi][ni][r] + bv;
      }
    }
  }
}

extern "C" void kernel_launch(void* const* d_in, const int* in_sizes, int n_in,
                              void* d_out, int out_size, void* d_ws, size_t ws_size,
                              hipStream_t stream) {
  const float* x  = (const float*)d_in[0];
  const float* W1 = (const float*)d_in[1];
  const float* b1 = (const float*)d_in[2];
  const float* A1 = (const float*)d_in[3];
  const float* B1 = (const float*)d_in[4];
  const float* W2 = (const float*)d_in[5];
  const float* b2 = (const float*)d_in[6];
  const float* A2 = (const float*)d_in[7];
  const float* B2 = (const float*)d_in[8];
  float* out = (float*)d_out;

  char* ws = (char*)d_ws;
  bf16_t* xb    = (bf16_t*)ws;                             // 19,365,888 B (pad)
  bf16_t* W1eff = (bf16_t*)(ws + 19366144);                //  4,718,592 B
  bf16_t* W2eff = (bf16_t*)(ws + 19366144 + 4718592);      //  4,718,592 B
  bf16_t* hbuf  = (bf16_t*)(ws + 19366144 + 2 * 4718592);  // 77,463,552 B

  const long nx = (long)M_ROWS * D_DIM;
  cast_f32_bf16_kernel<<<(int)((nx / 4 + 255) / 256), 256, 0, stream>>>(x, xb, nx);

  const int foldBlocks = (H_DIM * D_DIM + 255) / 256;
  fold_lora_kernel<<<foldBlocks, 256, 0, stream>>>(W1, A1, B1, W1eff, H_DIM, D_DIM);
  fold_lora_kernel<<<foldBlocks, 256, 0, stream>>>(W2, A2, B2, W2eff, D_DIM, H_DIM);

  // GEMM1: 256x128 tiles, XCD-banded 1-D grid: 7 rbands * 24 cols * 8 xcds
  gemm1_kernel<<<1344, 256, 0, stream>>>(xb, W1eff, b1, hbuf, M_ROWS, H_DIM, D_DIM);
  // GEMM2: 128x128 tiles, XCD-banded 1-D grid: 13 rbands * 6 cols * 8 xcds
  gemm2_kernel<<<624, 256, 0, stream>>>(hbuf, W2eff, b2, out, M_ROWS, D_DIM, H_DIM);
}